// Round 15
// baseline (141.381 us; speedup 1.0000x reference)
//
#include <hip/hip_runtime.h>

#define DMODEL 128
#define NEG_SLOPE 0.01f
#define NPB 64              // nodes per bucket
#define NBK_MAX 1600        // max buckets supported by LDS arrays (N <= 102400)
#define CPAD 16             // counter padding (ints) -> one counter per 64B line
#define SBLK 256            // hist/scat chunk blocks
#define CAP 1536            // static slab capacity per bucket (mean 1024 + 16 sigma)
#define OCAP 65536          // overflow spill capacity (entries)

typedef unsigned int uint;
typedef unsigned short ushort_t;
typedef __attribute__((ext_vector_type(8))) short short8v;   // 8 bf16 (4 VGPRs)
typedef __attribute__((ext_vector_type(4))) float float4v;   // MFMA acc

// round-to-nearest-even f32 -> bf16
__device__ inline ushort_t f2bf(float f) {
    uint u = __float_as_uint(f);
    u += 0x7FFFu + ((u >> 16) & 1u);
    return (ushort_t)(u >> 16);
}

// ---------------------------------------------------------------------------
// Pre: blocks 0..63 build Wt[c][k] = bf16(W[k][c]); block 64 zeroes ocnt.
// ---------------------------------------------------------------------------
__global__ __launch_bounds__(256) void k_pre(const float* __restrict__ W,
                                             ushort_t* __restrict__ Wt,
                                             int* __restrict__ ocnt) {
    const int b = blockIdx.x;
    if (b < 64) {
        const int t = b * 256 + threadIdx.x;          // 16384 threads
        const int k = t >> 7, c = t & 127;
        Wt[(size_t)c * DMODEL + k] = f2bf(W[(size_t)k * DMODEL + c]);
    } else if (threadIdx.x == 0) {
        *ocnt = 0;
    }
}

// ---------------------------------------------------------------------------
// Fused bucket-histogram || GEMM (R14, unchanged).
// ---------------------------------------------------------------------------
__global__ __launch_bounds__(256) void k_gh(
        const int* __restrict__ er, int* __restrict__ bcnt,
        int E, int NBK, int chunk,
        const float* __restrict__ X, const ushort_t* __restrict__ Wt,
        ushort_t* __restrict__ H, int N) {
    __shared__ __align__(16) char smem[16384];
    const int t = threadIdx.x;
    const int g = blockIdx.x;

    if (g < SBLK) {
        // ---------------- histogram branch ----------------
        int* lh = (int*)smem;
        for (int k = t; k < NBK; k += 256) lh[k] = 0;
        __syncthreads();
        const int s0 = g * chunk;               // chunk multiple of 4
        const int s1 = min(E, s0 + chunk);
        for (int i = s0 + t * 4; i < s1; i += 1024) {
            if (i + 3 < s1) {
                int4 r = *(const int4*)(er + i);
                atomicAdd(&lh[r.x >> 6], 1);
                atomicAdd(&lh[r.y >> 6], 1);
                atomicAdd(&lh[r.z >> 6], 1);
                atomicAdd(&lh[r.w >> 6], 1);
            } else {
                for (int q = i; q < s1; ++q) atomicAdd(&lh[er[q] >> 6], 1);
            }
        }
        __syncthreads();
        int* brow = bcnt + (size_t)g * NBK;
        for (int k = t; k < NBK; k += 256) brow[k] = lh[k];   // coalesced
    } else {
        // ---------------- GEMM branch (R10 tile, verbatim) ----------------
        ushort_t* Xs = (ushort_t*)smem;          // 64 x 128 bf16
        const int row0 = (g - SBLK) * 64;
#pragma unroll
        for (int i = 0; i < 8; ++i) {
            const int f = t + i * 256;      // 0..2047
            const int r = f >> 5;
            const int c4 = f & 31;
            float4 v = make_float4(0.f, 0.f, 0.f, 0.f);
            if (row0 + r < N) v = *(const float4*)(X + (size_t)(row0 + r) * DMODEL + c4 * 4);
            ushort4 u;
            u.x = f2bf(v.x); u.y = f2bf(v.y); u.z = f2bf(v.z); u.w = f2bf(v.w);
            const int chunk16 = (c4 >> 1) ^ (r & 7);
            *(ushort4*)(Xs + r * 128 + chunk16 * 8 + (c4 & 1) * 4) = u;
        }
        __syncthreads();

        const int wid = t >> 6, lane = t & 63;
        const int lr = lane & 15;
        const int kg = lane >> 4;
        const int wr = wid * 16 + lr;
        const ushort_t* wtb = Wt + (size_t)lr * DMODEL + kg * 8;

        float4v acc[8] = {};
#pragma unroll
        for (int s = 0; s < 4; ++s) {
            const int chunk16 = (s * 4 + kg) ^ (lr & 7);
            const short8v af = *(const short8v*)(Xs + wr * 128 + chunk16 * 8);
#pragma unroll
            for (int c = 0; c < 8; ++c) {
                const short8v bf = *(const short8v*)(wtb + (size_t)c * 16 * DMODEL + s * 32);
                acc[c] = __builtin_amdgcn_mfma_f32_16x16x32_bf16(af, bf, acc[c], 0, 0, 0);
            }
        }
#pragma unroll
        for (int c = 0; c < 8; ++c) {
#pragma unroll
            for (int r = 0; r < 4; ++r) {
                const int row = row0 + wid * 16 + kg * 4 + r;
                if (row < N) H[(size_t)row * DMODEL + c * 16 + lr] = f2bf(acc[c][r]);
            }
        }
    }
}

// ---------------------------------------------------------------------------
// boff (R14, unchanged): exact per-(block,bucket) slab offsets + totals.
// ---------------------------------------------------------------------------
__global__ __launch_bounds__(256) void k_boff(const int* __restrict__ bcnt,
                                              int* __restrict__ boff,
                                              int* __restrict__ cur, int NBK) {
    const int wid = threadIdx.x >> 6, l = threadIdx.x & 63;
    const int b = blockIdx.x * 4 + wid;
    if (b >= NBK) return;
    int c0 = bcnt[(size_t)(4 * l + 0) * NBK + b];
    int c1 = bcnt[(size_t)(4 * l + 1) * NBK + b];
    int c2 = bcnt[(size_t)(4 * l + 2) * NBK + b];
    int c3 = bcnt[(size_t)(4 * l + 3) * NBK + b];
    int s = c0 + c1 + c2 + c3;
    int ps = s;
    for (int o = 1; o < 64; o <<= 1) {
        int x = __shfl_up(ps, o);
        if (l >= o) ps += x;
    }
    const int base = ps - s;                   // exclusive prefix (slab-local)
    boff[(size_t)(4 * l + 0) * NBK + b] = base;
    boff[(size_t)(4 * l + 1) * NBK + b] = base + c0;
    boff[(size_t)(4 * l + 2) * NBK + b] = base + c0 + c1;
    boff[(size_t)(4 * l + 3) * NBK + b] = base + c0 + c1 + c2;
    if (l == 63) cur[b * CPAD] = ps;           // bucket total
}

// ---------------------------------------------------------------------------
// Single-pass scatter (R14, unchanged).
// ---------------------------------------------------------------------------
__global__ __launch_bounds__(1024) void k_scat(const int* __restrict__ er,
                                               const int* __restrict__ ec,
                                               const float* __restrict__ ev,
                                               const int* __restrict__ boff,
                                               int* __restrict__ ocnt,
                                               int4* __restrict__ ovf,
                                               int2* __restrict__ packed0,
                                               int E, int NBK, int chunk) {
    __shared__ int lh[NBK_MAX];
    const int t = threadIdx.x;
    const int* brow = boff + (size_t)blockIdx.x * NBK;
    for (int k = t; k < NBK; k += 1024) lh[k] = brow[k];   // coalesced
    __syncthreads();
    const int s0 = blockIdx.x * chunk;          // multiple of 4
    const int s1 = min(E, s0 + chunk);
    for (int i = s0 + t * 4; i < s1; i += 4096) {
        if (i + 3 < s1) {
            int4 r = *(const int4*)(er + i);
            int4 c = *(const int4*)(ec + i);
            float4 v = *(const float4*)(ev + i);
            int bkt, rl, slot;
#define SCAT1(RR, CC, VV)                                                     \
            bkt = (RR) >> 6; rl = (RR) & 63;                                  \
            slot = atomicAdd(&lh[bkt], 1);                                    \
            if (slot < CAP)                                                   \
                packed0[(size_t)bkt * CAP + slot] =                           \
                    make_int2((rl << 17) | (CC), __float_as_int(VV));         \
            else {                                                            \
                int o = atomicAdd(ocnt, 1);                                   \
                if (o < OCAP) ovf[o] = make_int4(bkt, rl, (CC), __float_as_int(VV)); \
            }
            SCAT1(r.x, c.x, v.x)
            SCAT1(r.y, c.y, v.y)
            SCAT1(r.z, c.z, v.z)
            SCAT1(r.w, c.w, v.w)
        } else {
            for (int q = i; q < s1; ++q) {
                int rr = er[q];
                int bkt = rr >> 6, rl = rr & 63;
                int slot = atomicAdd(&lh[bkt], 1);
                if (slot < CAP)
                    packed0[(size_t)bkt * CAP + slot] =
                        make_int2((rl << 17) | ec[q], __float_as_int(ev[q]));
                else {
                    int o = atomicAdd(ocnt, 1);
                    if (o < OCAP) ovf[o] = make_int4(bkt, rl, ec[q], __float_as_int(ev[q]));
                }
            }
        }
    }
}

// ---------------------------------------------------------------------------
// Regroup + aggregate, 2-PASS COLUMN SPLIT: regroup (phases 1-3) once, then
// aggregate in two passes over column halves. Pass p gathers only line p of
// each H row (32 lanes x 4B = one 128B line) -> per-pass working set 12.8 MB
// (vs 25.6) -> higher L2 hit rate on the ~2.7 TB/s miss path.
// ---------------------------------------------------------------------------
#define EDGE_FMA2(EE, GG)                                                     \
    {                                                                         \
        const float v_ = __int_as_float((EE).y);                              \
        acc.x = fmaf(v_, __uint_as_float((GG) << 16), acc.x);                 \
        acc.y = fmaf(v_, __uint_as_float((GG) & 0xffff0000u), acc.y);         \
    }

__global__ __launch_bounds__(256) void k_bagg2(const uint* __restrict__ Hb,
                                               const int* __restrict__ cur,
                                               const int* __restrict__ ocnt,
                                               const int4* __restrict__ ovf,
                                               const int2* __restrict__ packed0,
                                               const float* __restrict__ bias,
                                               float* __restrict__ out, int N) {
    __shared__ int2 srt[CAP];
    __shared__ int lcnt[NPB];
    __shared__ int lpref[NPB];
    __shared__ int lcur[NPB];
    const int t = threadIdx.x;
    const int b = blockIdx.x;
    if (t < NPB) { lcnt[t] = 0; lcur[t] = 0; }
    __syncthreads();

    const int cnt = cur[b * CPAD];
    const int staged = min(cnt, CAP);
    const int2* slab = packed0 + (size_t)b * CAP;

    // phase 1: load + count (entries kept in registers)
    int2 myent[6];
#pragma unroll
    for (int k = 0; k < 6; ++k) {
        const int i = t + k * 256;
        myent[k] = make_int2(0, 0);
        if (i < staged) {
            myent[k] = slab[i];
            atomicAdd(&lcnt[((uint)myent[k].x) >> 17], 1);
        }
    }
    __syncthreads();

    // phase 2: exclusive prefix over 64 counters
    if (t < NPB) {
        int p = 0;
        for (int k = 0; k < t; ++k) p += lcnt[k];
        lpref[t] = p;
    }
    __syncthreads();

    // phase 3: permute into per-node-contiguous LDS buffer
#pragma unroll
    for (int k = 0; k < 6; ++k) {
        const int i = t + k * 256;
        if (i < staged) {
            const int rl = ((uint)myent[k].x) >> 17;
            const int pos = lpref[rl] + atomicAdd(&lcur[rl], 1);
            srt[pos] = make_int2(myent[k].x & 0x1FFFF, myent[k].y);
        }
    }
    __syncthreads();

    // phase 4: aggregate in 2 column passes; wave w -> nodes [w*16, w*16+16)
    const int wid = t >> 6, lane = t & 63;
    const int h = lane >> 5, sl = lane & 31;
    const int oc = min(*ocnt, OCAP);

    for (int pass = 0; pass < 2; ++pass) {
        const uint* Hp = Hb + pass * 32;                 // +128B line offset
        const float2 bv = ((const float2*)(bias + pass * 64))[sl];
        for (int r = wid * 16; r < wid * 16 + 16; ++r) {
            const int node = b * NPB + r;
            if (node >= N) continue;
            const int m = lcnt[r], p0 = lpref[r];
            float2 acc = make_float2(0.f, 0.f);
            int jj = h;
            for (; jj + 14 < m; jj += 16) {
                const int2 e0 = srt[p0 + jj];
                const int2 e1 = srt[p0 + jj + 2];
                const int2 e2 = srt[p0 + jj + 4];
                const int2 e3 = srt[p0 + jj + 6];
                const int2 e4 = srt[p0 + jj + 8];
                const int2 e5 = srt[p0 + jj + 10];
                const int2 e6 = srt[p0 + jj + 12];
                const int2 e7 = srt[p0 + jj + 14];
                const uint g0 = Hp[(size_t)e0.x * 64 + sl];
                const uint g1 = Hp[(size_t)e1.x * 64 + sl];
                const uint g2 = Hp[(size_t)e2.x * 64 + sl];
                const uint g3 = Hp[(size_t)e3.x * 64 + sl];
                const uint g4 = Hp[(size_t)e4.x * 64 + sl];
                const uint g5 = Hp[(size_t)e5.x * 64 + sl];
                const uint g6 = Hp[(size_t)e6.x * 64 + sl];
                const uint g7 = Hp[(size_t)e7.x * 64 + sl];
                EDGE_FMA2(e0, g0) EDGE_FMA2(e1, g1) EDGE_FMA2(e2, g2) EDGE_FMA2(e3, g3)
                EDGE_FMA2(e4, g4) EDGE_FMA2(e5, g5) EDGE_FMA2(e6, g6) EDGE_FMA2(e7, g7)
            }
            for (; jj + 6 < m; jj += 8) {
                const int2 e0 = srt[p0 + jj];
                const int2 e1 = srt[p0 + jj + 2];
                const int2 e2 = srt[p0 + jj + 4];
                const int2 e3 = srt[p0 + jj + 6];
                const uint g0 = Hp[(size_t)e0.x * 64 + sl];
                const uint g1 = Hp[(size_t)e1.x * 64 + sl];
                const uint g2 = Hp[(size_t)e2.x * 64 + sl];
                const uint g3 = Hp[(size_t)e3.x * 64 + sl];
                EDGE_FMA2(e0, g0) EDGE_FMA2(e1, g1) EDGE_FMA2(e2, g2) EDGE_FMA2(e3, g3)
            }
            for (; jj < m; jj += 2) {
                const int2 e0 = srt[p0 + jj];
                const uint g0 = Hp[(size_t)e0.x * 64 + sl];
                EDGE_FMA2(e0, g0)
            }
            // overflow spill (normally oc == 0)
            for (int i = 0; i < oc; ++i) {
                const int4 o4 = ovf[i];
                if (o4.x == b && o4.y == r && h == 0) {
                    const float v = __int_as_float(o4.w);
                    const uint g = Hp[(size_t)o4.z * 64 + sl];
                    acc.x = fmaf(v, __uint_as_float(g << 16), acc.x);
                    acc.y = fmaf(v, __uint_as_float(g & 0xffff0000u), acc.y);
                }
            }
            acc.x += __shfl_xor(acc.x, 32);
            acc.y += __shfl_xor(acc.y, 32);
            if (h == 0) {
                float2 o;
                o.x = acc.x + bv.x;
                o.y = acc.y + bv.y;
                o.x = o.x >= 0.f ? o.x : NEG_SLOPE * o.x;
                o.y = o.y >= 0.f ? o.y : NEG_SLOPE * o.y;
                ((float2*)(out + (size_t)node * DMODEL + pass * 64))[sl] = o;
            }
        }
    }
}

// ---------------------------------------------------------------------------
extern "C" void kernel_launch(void* const* d_in, const int* in_sizes, int n_in,
                              void* d_out, int out_size, void* d_ws, size_t ws_size,
                              hipStream_t stream) {
    const float* X    = (const float*)d_in[0];
    const int*   er   = (const int*)d_in[1];
    const int*   ec   = (const int*)d_in[2];
    const float* ev   = (const float*)d_in[3];
    const float* W    = (const float*)d_in[4];
    const float* bias = (const float*)d_in[5];
    float* out = (float*)d_out;

    const int N = in_sizes[0] / DMODEL;
    const int E = in_sizes[1];
    const int NBK = (N + NPB - 1) / NPB;   // 1563 for N=100000 (<= NBK_MAX)

    // workspace layout (128B-aligned slabs)
    char* ws = (char*)d_ws;
    size_t off = 0;
    auto alloc = [&](size_t bytes) {
        void* p = ws + off;
        off += (bytes + 127) & ~(size_t)127;
        return p;
    };
    ushort_t* H   = (ushort_t*)alloc((size_t)N * DMODEL * sizeof(ushort_t));
    ushort_t* Wt  = (ushort_t*)alloc((size_t)DMODEL * DMODEL * sizeof(ushort_t));
    int* cur      = (int*)alloc(((size_t)NBK * CPAD + 1) * sizeof(int));  // +ocnt
    int* ocnt     = cur + (size_t)NBK * CPAD;
    int* bcnt     = (int*)alloc((size_t)SBLK * NBK * sizeof(int));
    int* boff     = (int*)alloc((size_t)SBLK * NBK * sizeof(int));
    int4* ovf     = (int4*)alloc((size_t)OCAP * sizeof(int4));
    int2* packed0 = (int2*)alloc((size_t)NBK * CAP * sizeof(int2));
    (void)ws_size;

    // 1) pre: Wt transpose + zero ocnt
    hipLaunchKernelGGL(k_pre, dim3(65), dim3(256), 0, stream, W, Wt, ocnt);

    // 2) fused histogram || GEMM
    const int GB = (N + 63) / 64;                            // 1563 gemm blocks
    const int chunk = ((((E + SBLK - 1) / SBLK) + 3) & ~3);  // multiple of 4
    hipLaunchKernelGGL(k_gh, dim3(SBLK + GB), dim3(256), 0, stream,
                       er, bcnt, E, NBK, chunk, X, Wt, H, N);

    // 3) exact per-(block,bucket) offsets + bucket totals
    hipLaunchKernelGGL(k_boff, dim3((NBK + 3) / 4), dim3(256), 0, stream,
                       bcnt, boff, cur, NBK);

    // 4) single-pass scatter
    hipLaunchKernelGGL(k_scat, dim3(SBLK), dim3(1024), 0, stream,
                       er, ec, ev, boff, ocnt, ovf, packed0, E, NBK, chunk);

    // 5) regroup + aggregate (2-pass column split), one block per bucket
    hipLaunchKernelGGL(k_bagg2, dim3(NBK), dim3(256), 0, stream,
                       (const uint*)H, cur, ocnt, ovf, packed0, bias, out, N);
}

// Round 16
// 136.952 us; speedup vs baseline: 1.0323x; 1.0323x over previous
//
#include <hip/hip_runtime.h>

#define DMODEL 128
#define NEG_SLOPE 0.01f
#define NPB 64              // nodes per bucket
#define NBK_MAX 1600        // max buckets supported by LDS arrays (N <= 102400)
#define CPAD 16             // counter padding (ints) -> one counter per 64B line
#define SBLK 256            // hist/scat chunk blocks
#define CAP 1536            // static slab capacity per bucket (mean 1024 + 16 sigma)
#define OCAP 65536          // overflow spill capacity (entries)

typedef unsigned int uint;
typedef unsigned short ushort_t;
typedef __attribute__((ext_vector_type(8))) short short8v;   // 8 bf16 (4 VGPRs)
typedef __attribute__((ext_vector_type(4))) float float4v;   // MFMA acc

// round-to-nearest-even f32 -> bf16
__device__ inline ushort_t f2bf(float f) {
    uint u = __float_as_uint(f);
    u += 0x7FFFu + ((u >> 16) & 1u);
    return (ushort_t)(u >> 16);
}

// ---------------------------------------------------------------------------
// Pre: blocks 0..63 build Wt[c][k] = bf16(W[k][c]); block 64 zeroes ocnt.
// ---------------------------------------------------------------------------
__global__ __launch_bounds__(256) void k_pre(const float* __restrict__ W,
                                             ushort_t* __restrict__ Wt,
                                             int* __restrict__ ocnt) {
    const int b = blockIdx.x;
    if (b < 64) {
        const int t = b * 256 + threadIdx.x;          // 16384 threads
        const int k = t >> 7, c = t & 127;
        Wt[(size_t)c * DMODEL + k] = f2bf(W[(size_t)k * DMODEL + c]);
    } else if (threadIdx.x == 0) {
        *ocnt = 0;
    }
}

// ---------------------------------------------------------------------------
// Fused bucket-histogram || GEMM. blocks [0,SBLK): hist -> bcnt[blk][bucket]
// (no global atomics). blocks [SBLK,..): swizzled-LDS MFMA gemm (64 rows).
// ---------------------------------------------------------------------------
__global__ __launch_bounds__(256) void k_gh(
        const int* __restrict__ er, int* __restrict__ bcnt,
        int E, int NBK, int chunk,
        const float* __restrict__ X, const ushort_t* __restrict__ Wt,
        ushort_t* __restrict__ H, int N) {
    __shared__ __align__(16) char smem[16384];
    const int t = threadIdx.x;
    const int g = blockIdx.x;

    if (g < SBLK) {
        // ---------------- histogram branch ----------------
        int* lh = (int*)smem;
        for (int k = t; k < NBK; k += 256) lh[k] = 0;
        __syncthreads();
        const int s0 = g * chunk;               // chunk multiple of 4
        const int s1 = min(E, s0 + chunk);
        for (int i = s0 + t * 4; i < s1; i += 1024) {
            if (i + 3 < s1) {
                int4 r = *(const int4*)(er + i);
                atomicAdd(&lh[r.x >> 6], 1);
                atomicAdd(&lh[r.y >> 6], 1);
                atomicAdd(&lh[r.z >> 6], 1);
                atomicAdd(&lh[r.w >> 6], 1);
            } else {
                for (int q = i; q < s1; ++q) atomicAdd(&lh[er[q] >> 6], 1);
            }
        }
        __syncthreads();
        int* brow = bcnt + (size_t)g * NBK;
        for (int k = t; k < NBK; k += 256) brow[k] = lh[k];   // coalesced
    } else {
        // ---------------- GEMM branch ----------------
        ushort_t* Xs = (ushort_t*)smem;          // 64 x 128 bf16
        const int row0 = (g - SBLK) * 64;
#pragma unroll
        for (int i = 0; i < 8; ++i) {
            const int f = t + i * 256;      // 0..2047
            const int r = f >> 5;
            const int c4 = f & 31;
            float4 v = make_float4(0.f, 0.f, 0.f, 0.f);
            if (row0 + r < N) v = *(const float4*)(X + (size_t)(row0 + r) * DMODEL + c4 * 4);
            ushort4 u;
            u.x = f2bf(v.x); u.y = f2bf(v.y); u.z = f2bf(v.z); u.w = f2bf(v.w);
            const int chunk16 = (c4 >> 1) ^ (r & 7);
            *(ushort4*)(Xs + r * 128 + chunk16 * 8 + (c4 & 1) * 4) = u;
        }
        __syncthreads();

        const int wid = t >> 6, lane = t & 63;
        const int lr = lane & 15;
        const int kg = lane >> 4;
        const int wr = wid * 16 + lr;
        const ushort_t* wtb = Wt + (size_t)lr * DMODEL + kg * 8;

        float4v acc[8] = {};
#pragma unroll
        for (int s = 0; s < 4; ++s) {
            const int chunk16 = (s * 4 + kg) ^ (lr & 7);
            const short8v af = *(const short8v*)(Xs + wr * 128 + chunk16 * 8);
#pragma unroll
            for (int c = 0; c < 8; ++c) {
                const short8v bf = *(const short8v*)(wtb + (size_t)c * 16 * DMODEL + s * 32);
                acc[c] = __builtin_amdgcn_mfma_f32_16x16x32_bf16(af, bf, acc[c], 0, 0, 0);
            }
        }
#pragma unroll
        for (int c = 0; c < 8; ++c) {
#pragma unroll
            for (int r = 0; r < 4; ++r) {
                const int row = row0 + wid * 16 + kg * 4 + r;
                if (row < N) H[(size_t)row * DMODEL + c * 16 + lr] = f2bf(acc[c][r]);
            }
        }
    }
}

// ---------------------------------------------------------------------------
// boff: exact per-(block,bucket) slab offsets + bucket totals.
// ---------------------------------------------------------------------------
__global__ __launch_bounds__(256) void k_boff(const int* __restrict__ bcnt,
                                              int* __restrict__ boff,
                                              int* __restrict__ cur, int NBK) {
    const int wid = threadIdx.x >> 6, l = threadIdx.x & 63;
    const int b = blockIdx.x * 4 + wid;
    if (b >= NBK) return;
    int c0 = bcnt[(size_t)(4 * l + 0) * NBK + b];
    int c1 = bcnt[(size_t)(4 * l + 1) * NBK + b];
    int c2 = bcnt[(size_t)(4 * l + 2) * NBK + b];
    int c3 = bcnt[(size_t)(4 * l + 3) * NBK + b];
    int s = c0 + c1 + c2 + c3;
    int ps = s;
    for (int o = 1; o < 64; o <<= 1) {
        int x = __shfl_up(ps, o);
        if (l >= o) ps += x;
    }
    const int base = ps - s;                   // exclusive prefix (slab-local)
    boff[(size_t)(4 * l + 0) * NBK + b] = base;
    boff[(size_t)(4 * l + 1) * NBK + b] = base + c0;
    boff[(size_t)(4 * l + 2) * NBK + b] = base + c0 + c1;
    boff[(size_t)(4 * l + 3) * NBK + b] = base + c0 + c1 + c2;
    if (l == 63) cur[b * CPAD] = ps;           // bucket total
}

// ---------------------------------------------------------------------------
// Single-pass scatter: LDS cursors preloaded from boff (exact, disjoint).
// entry: x=(rl<<17)|col ; y=value
// ---------------------------------------------------------------------------
__global__ __launch_bounds__(1024) void k_scat(const int* __restrict__ er,
                                               const int* __restrict__ ec,
                                               const float* __restrict__ ev,
                                               const int* __restrict__ boff,
                                               int* __restrict__ ocnt,
                                               int4* __restrict__ ovf,
                                               int2* __restrict__ packed0,
                                               int E, int NBK, int chunk) {
    __shared__ int lh[NBK_MAX];
    const int t = threadIdx.x;
    const int* brow = boff + (size_t)blockIdx.x * NBK;
    for (int k = t; k < NBK; k += 1024) lh[k] = brow[k];   // coalesced
    __syncthreads();
    const int s0 = blockIdx.x * chunk;          // multiple of 4
    const int s1 = min(E, s0 + chunk);
    for (int i = s0 + t * 4; i < s1; i += 4096) {
        if (i + 3 < s1) {
            int4 r = *(const int4*)(er + i);
            int4 c = *(const int4*)(ec + i);
            float4 v = *(const float4*)(ev + i);
            int bkt, rl, slot;
#define SCAT1(RR, CC, VV)                                                     \
            bkt = (RR) >> 6; rl = (RR) & 63;                                  \
            slot = atomicAdd(&lh[bkt], 1);                                    \
            if (slot < CAP)                                                   \
                packed0[(size_t)bkt * CAP + slot] =                           \
                    make_int2((rl << 17) | (CC), __float_as_int(VV));         \
            else {                                                            \
                int o = atomicAdd(ocnt, 1);                                   \
                if (o < OCAP) ovf[o] = make_int4(bkt, rl, (CC), __float_as_int(VV)); \
            }
            SCAT1(r.x, c.x, v.x)
            SCAT1(r.y, c.y, v.y)
            SCAT1(r.z, c.z, v.z)
            SCAT1(r.w, c.w, v.w)
        } else {
            for (int q = i; q < s1; ++q) {
                int rr = er[q];
                int bkt = rr >> 6, rl = rr & 63;
                int slot = atomicAdd(&lh[bkt], 1);
                if (slot < CAP)
                    packed0[(size_t)bkt * CAP + slot] =
                        make_int2((rl << 17) | ec[q], __float_as_int(ev[q]));
                else {
                    int o = atomicAdd(ocnt, 1);
                    if (o < OCAP) ovf[o] = make_int4(bkt, rl, ec[q], __float_as_int(ev[q]));
                }
            }
        }
    }
}

// ---------------------------------------------------------------------------
// Regroup + aggregate (R14 version): one 256-thread block per bucket.
// Single pass, float4 acc (uint2 gathers), 8 gathers in flight per half.
// ---------------------------------------------------------------------------
#define EDGE_FMA(EE, GG)                                                      \
    {                                                                         \
        const float v_ = __int_as_float((EE).y);                              \
        acc.x = fmaf(v_, __uint_as_float((GG).x << 16), acc.x);               \
        acc.y = fmaf(v_, __uint_as_float((GG).x & 0xffff0000u), acc.y);       \
        acc.z = fmaf(v_, __uint_as_float((GG).y << 16), acc.z);               \
        acc.w = fmaf(v_, __uint_as_float((GG).y & 0xffff0000u), acc.w);       \
    }

__global__ __launch_bounds__(256) void k_bagg2(const uint* __restrict__ Hb,
                                               const int* __restrict__ cur,
                                               const int* __restrict__ ocnt,
                                               const int4* __restrict__ ovf,
                                               const int2* __restrict__ packed0,
                                               const float* __restrict__ bias,
                                               float* __restrict__ out, int N) {
    __shared__ int2 srt[CAP];
    __shared__ int lcnt[NPB];
    __shared__ int lpref[NPB];
    __shared__ int lcur[NPB];
    const int t = threadIdx.x;
    const int b = blockIdx.x;
    if (t < NPB) { lcnt[t] = 0; lcur[t] = 0; }
    __syncthreads();

    const int cnt = cur[b * CPAD];
    const int staged = min(cnt, CAP);
    const int2* slab = packed0 + (size_t)b * CAP;

    // phase 1: load + count (entries kept in registers)
    int2 myent[6];
#pragma unroll
    for (int k = 0; k < 6; ++k) {
        const int i = t + k * 256;
        myent[k] = make_int2(0, 0);
        if (i < staged) {
            myent[k] = slab[i];
            atomicAdd(&lcnt[((uint)myent[k].x) >> 17], 1);
        }
    }
    __syncthreads();

    // phase 2: exclusive prefix over 64 counters
    if (t < NPB) {
        int p = 0;
        for (int k = 0; k < t; ++k) p += lcnt[k];
        lpref[t] = p;
    }
    __syncthreads();

    // phase 3: permute into per-node-contiguous LDS buffer
#pragma unroll
    for (int k = 0; k < 6; ++k) {
        const int i = t + k * 256;
        if (i < staged) {
            const int rl = ((uint)myent[k].x) >> 17;
            const int pos = lpref[rl] + atomicAdd(&lcur[rl], 1);
            srt[pos] = make_int2(myent[k].x & 0x1FFFF, myent[k].y);
        }
    }
    __syncthreads();

    // phase 4: aggregate; wave w -> nodes [w*16, w*16+16)
    const int wid = t >> 6, lane = t & 63;
    const int h = lane >> 5, sl = lane & 31;
    const float4 bv = ((const float4*)bias)[sl];
    const int oc = min(*ocnt, OCAP);

    for (int r = wid * 16; r < wid * 16 + 16; ++r) {
        const int node = b * NPB + r;
        if (node >= N) continue;
        const int m = lcnt[r], p0 = lpref[r];
        float4 acc = make_float4(0.f, 0.f, 0.f, 0.f);
        int jj = h;
        for (; jj + 14 < m; jj += 16) {
            const int2 e0 = srt[p0 + jj];
            const int2 e1 = srt[p0 + jj + 2];
            const int2 e2 = srt[p0 + jj + 4];
            const int2 e3 = srt[p0 + jj + 6];
            const int2 e4 = srt[p0 + jj + 8];
            const int2 e5 = srt[p0 + jj + 10];
            const int2 e6 = srt[p0 + jj + 12];
            const int2 e7 = srt[p0 + jj + 14];
            const uint2 g0 = ((const uint2*)(Hb + (size_t)e0.x * 64))[sl];
            const uint2 g1 = ((const uint2*)(Hb + (size_t)e1.x * 64))[sl];
            const uint2 g2 = ((const uint2*)(Hb + (size_t)e2.x * 64))[sl];
            const uint2 g3 = ((const uint2*)(Hb + (size_t)e3.x * 64))[sl];
            const uint2 g4 = ((const uint2*)(Hb + (size_t)e4.x * 64))[sl];
            const uint2 g5 = ((const uint2*)(Hb + (size_t)e5.x * 64))[sl];
            const uint2 g6 = ((const uint2*)(Hb + (size_t)e6.x * 64))[sl];
            const uint2 g7 = ((const uint2*)(Hb + (size_t)e7.x * 64))[sl];
            EDGE_FMA(e0, g0) EDGE_FMA(e1, g1) EDGE_FMA(e2, g2) EDGE_FMA(e3, g3)
            EDGE_FMA(e4, g4) EDGE_FMA(e5, g5) EDGE_FMA(e6, g6) EDGE_FMA(e7, g7)
        }
        for (; jj + 6 < m; jj += 8) {
            const int2 e0 = srt[p0 + jj];
            const int2 e1 = srt[p0 + jj + 2];
            const int2 e2 = srt[p0 + jj + 4];
            const int2 e3 = srt[p0 + jj + 6];
            const uint2 g0 = ((const uint2*)(Hb + (size_t)e0.x * 64))[sl];
            const uint2 g1 = ((const uint2*)(Hb + (size_t)e1.x * 64))[sl];
            const uint2 g2 = ((const uint2*)(Hb + (size_t)e2.x * 64))[sl];
            const uint2 g3 = ((const uint2*)(Hb + (size_t)e3.x * 64))[sl];
            EDGE_FMA(e0, g0) EDGE_FMA(e1, g1) EDGE_FMA(e2, g2) EDGE_FMA(e3, g3)
        }
        for (; jj < m; jj += 2) {
            const int2 e0 = srt[p0 + jj];
            const uint2 g0 = ((const uint2*)(Hb + (size_t)e0.x * 64))[sl];
            EDGE_FMA(e0, g0)
        }
        // overflow spill (normally oc == 0)
        for (int i = 0; i < oc; ++i) {
            const int4 o4 = ovf[i];
            if (o4.x == b && o4.y == r && h == 0) {
                const float v = __int_as_float(o4.w);
                const uint2 g = ((const uint2*)(Hb + (size_t)o4.z * 64))[sl];
                acc.x = fmaf(v, __uint_as_float(g.x << 16), acc.x);
                acc.y = fmaf(v, __uint_as_float(g.x & 0xffff0000u), acc.y);
                acc.z = fmaf(v, __uint_as_float(g.y << 16), acc.z);
                acc.w = fmaf(v, __uint_as_float(g.y & 0xffff0000u), acc.w);
            }
        }
        acc.x += __shfl_xor(acc.x, 32);
        acc.y += __shfl_xor(acc.y, 32);
        acc.z += __shfl_xor(acc.z, 32);
        acc.w += __shfl_xor(acc.w, 32);
        if (h == 0) {
            float4 o;
            o.x = acc.x + bv.x; o.y = acc.y + bv.y;
            o.z = acc.z + bv.z; o.w = acc.w + bv.w;
            o.x = o.x >= 0.f ? o.x : NEG_SLOPE * o.x;
            o.y = o.y >= 0.f ? o.y : NEG_SLOPE * o.y;
            o.z = o.z >= 0.f ? o.z : NEG_SLOPE * o.z;
            o.w = o.w >= 0.f ? o.w : NEG_SLOPE * o.w;
            ((float4*)(out + (size_t)node * DMODEL))[sl] = o;
        }
    }
}

// ---------------------------------------------------------------------------
extern "C" void kernel_launch(void* const* d_in, const int* in_sizes, int n_in,
                              void* d_out, int out_size, void* d_ws, size_t ws_size,
                              hipStream_t stream) {
    const float* X    = (const float*)d_in[0];
    const int*   er   = (const int*)d_in[1];
    const int*   ec   = (const int*)d_in[2];
    const float* ev   = (const float*)d_in[3];
    const float* W    = (const float*)d_in[4];
    const float* bias = (const float*)d_in[5];
    float* out = (float*)d_out;

    const int N = in_sizes[0] / DMODEL;
    const int E = in_sizes[1];
    const int NBK = (N + NPB - 1) / NPB;   // 1563 for N=100000 (<= NBK_MAX)

    // workspace layout (128B-aligned slabs)
    char* ws = (char*)d_ws;
    size_t off = 0;
    auto alloc = [&](size_t bytes) {
        void* p = ws + off;
        off += (bytes + 127) & ~(size_t)127;
        return p;
    };
    ushort_t* H   = (ushort_t*)alloc((size_t)N * DMODEL * sizeof(ushort_t));
    ushort_t* Wt  = (ushort_t*)alloc((size_t)DMODEL * DMODEL * sizeof(ushort_t));
    int* cur      = (int*)alloc(((size_t)NBK * CPAD + 1) * sizeof(int));  // +ocnt
    int* ocnt     = cur + (size_t)NBK * CPAD;
    int* bcnt     = (int*)alloc((size_t)SBLK * NBK * sizeof(int));
    int* boff     = (int*)alloc((size_t)SBLK * NBK * sizeof(int));
    int4* ovf     = (int4*)alloc((size_t)OCAP * sizeof(int4));
    int2* packed0 = (int2*)alloc((size_t)NBK * CAP * sizeof(int2));
    (void)ws_size;

    // 1) pre: Wt transpose + zero ocnt
    hipLaunchKernelGGL(k_pre, dim3(65), dim3(256), 0, stream, W, Wt, ocnt);

    // 2) fused histogram || GEMM
    const int GB = (N + 63) / 64;                            // 1563 gemm blocks
    const int chunk = ((((E + SBLK - 1) / SBLK) + 3) & ~3);  // multiple of 4
    hipLaunchKernelGGL(k_gh, dim3(SBLK + GB), dim3(256), 0, stream,
                       er, bcnt, E, NBK, chunk, X, Wt, H, N);

    // 3) exact per-(block,bucket) offsets + bucket totals
    hipLaunchKernelGGL(k_boff, dim3((NBK + 3) / 4), dim3(256), 0, stream,
                       bcnt, boff, cur, NBK);

    // 4) single-pass scatter
    hipLaunchKernelGGL(k_scat, dim3(SBLK), dim3(1024), 0, stream,
                       er, ec, ev, boff, ocnt, ovf, packed0, E, NBK, chunk);

    // 5) regroup + aggregate, one 256-thread block per bucket
    hipLaunchKernelGGL(k_bagg2, dim3(NBK), dim3(256), 0, stream,
                       (const uint*)H, cur, ocnt, ovf, packed0, bias, out, N);
}